// Round 1
// baseline (244.383 us; speedup 1.0000x reference)
//
#include <hip/hip_runtime.h>
#include <stdint.h>

#define BB 32
#define TT 1024
#define CC 384
#define MAXMEL 4096
#define FPB 128  // frames per block (MAXMEL/FPB = 32 blocks per batch)

typedef float f4 __attribute__((ext_vector_type(4)));  // native vec4 for nt builtins

// Shuffle-based inclusive scan of dur[b][0..1023] into s_cs; returns total.
__device__ __forceinline__ int block_scan_1024(const int* __restrict__ dur, int b,
                                               int* s_cs) {
    __shared__ int s_wsum[16];
    const int tid = threadIdx.x;
    const int lane = tid & 63;
    const int wid = tid >> 6;
    int v = dur[b * TT + tid];
    #pragma unroll
    for (int off = 1; off < 64; off <<= 1) {
        int n = __shfl_up(v, off, 64);
        if (lane >= off) v += n;
    }
    if (lane == 63) s_wsum[wid] = v;
    __syncthreads();
    if (wid == 0 && lane < 16) {
        int w = s_wsum[lane];
        #pragma unroll
        for (int off = 1; off < 16; off <<= 1) {
            int n = __shfl_up(w, off, 64);
            if (lane >= off) w += n;
        }
        s_wsum[lane] = w;
    }
    __syncthreads();
    if (wid > 0) v += s_wsum[wid - 1];
    s_cs[tid] = v;
    __syncthreads();
    return s_cs[TT - 1];
}

// Single fused kernel: per-block scan (redundant, cheap, L2-hot) + branchless
// LDS binary search per frame + streaming gather with nontemporal stores.
// Grid (MAXMEL/FPB, BB) x 1024 threads; 32 lanes per frame, 4 frames per
// thread-group (unrolled -> 4 independent search chains for ILP).
__global__ __launch_bounds__(1024) void lr_fused(const float* __restrict__ x,
                                                 const int* __restrict__ dur,
                                                 float* __restrict__ out,
                                                 float* __restrict__ out_total) {
    __shared__ int s_cs[TT];
    const int b = blockIdx.y;
    const int tid = threadIdx.x;
    const int total = block_scan_1024(dur, b, s_cs);
    if (blockIdx.x == 0 && tid == 0) out_total[b] = (float)total;

    const int lane = tid & 31;
    const int f0 = blockIdx.x * FPB + (tid >> 5);
    const float* __restrict__ xb = x + (size_t)b * TT * CC;
    float* __restrict__ ob = out + (size_t)b * MAXMEL * CC;

    #pragma unroll
    for (int j = 0; j < FPB / 32; ++j) {
        const int frame = f0 + j * 32;
        f4* outp = (f4*)(ob + (size_t)frame * CC);
        if (frame < total) {
            // searchsorted(cs, frame, side='right'): count of cs[i] <= frame.
            // Fixed 10-step branchless form; all 32 lanes of a frame read the
            // same LDS address each step -> broadcast, conflict-free.
            int pos = 0;
            #pragma unroll
            for (int s = 512; s >= 1; s >>= 1) {
                if (s_cs[pos + s - 1] <= frame) pos += s;
            }
            const int t = min(pos, TT - 1);
            const f4* src = (const f4*)(xb + (size_t)t * CC);
            #pragma unroll
            for (int k = 0; k < 3; ++k)
                __builtin_nontemporal_store(src[lane + k * 32], &outp[lane + k * 32]);
        } else {
            const f4 z = {0.f, 0.f, 0.f, 0.f};
            #pragma unroll
            for (int k = 0; k < 3; ++k)
                __builtin_nontemporal_store(z, &outp[lane + k * 32]);
        }
    }
}

extern "C" void kernel_launch(void* const* d_in, const int* in_sizes, int n_in,
                              void* d_out, int out_size, void* d_ws, size_t ws_size,
                              hipStream_t stream) {
    const float* x = (const float*)d_in[0];
    const int* dur = (const int*)d_in[1];  // reference int64 -> int32 on device per harness
    float* out = (float*)d_out;
    float* out_total = out + (size_t)BB * MAXMEL * CC;  // 32 floats at the tail

    lr_fused<<<dim3(MAXMEL / FPB, BB), 1024, 0, stream>>>(x, dur, out, out_total);
}

// Round 2
// 239.214 us; speedup vs baseline: 1.0216x; 1.0216x over previous
//
#include <hip/hip_runtime.h>
#include <stdint.h>

#define BB 32
#define TT 1024
#define CC 384
#define MAXMEL 4096

typedef float f4 __attribute__((ext_vector_type(4)));  // native vec4 for nt builtins

// Shuffle-based inclusive scan of dur[b][0..1023] into s_cs; returns total.
__device__ __forceinline__ int block_scan_1024(const int* __restrict__ dur, int b,
                                               int* s_cs) {
    __shared__ int s_wsum[16];
    const int tid = threadIdx.x;
    const int lane = tid & 63;
    const int wid = tid >> 6;
    int v = dur[b * TT + tid];
    #pragma unroll
    for (int off = 1; off < 64; off <<= 1) {
        int n = __shfl_up(v, off, 64);
        if (lane >= off) v += n;
    }
    if (lane == 63) s_wsum[wid] = v;
    __syncthreads();
    if (wid == 0 && lane < 16) {
        int w = s_wsum[lane];
        #pragma unroll
        for (int off = 1; off < 16; off <<= 1) {
            int n = __shfl_up(w, off, 64);
            if (lane >= off) w += n;
        }
        s_wsum[lane] = w;
    }
    __syncthreads();
    if (wid > 0) v += s_wsum[wid - 1];
    s_cs[tid] = v;
    __syncthreads();
    return s_cs[TT - 1];
}

// ---------- Path A: tok precompute (u16, 256 KB ws) + streaming gather ----------

// Grid (4, BB): 4 blocks per batch, each redoes the cheap scan and searches
// 1024 frames (1 per thread) — 4x the occupancy of the single-block version.
__global__ __launch_bounds__(1024) void lr_scan_tok16(const int* __restrict__ dur,
                                                      uint16_t* __restrict__ tok,
                                                      float* __restrict__ out_total) {
    __shared__ int s_cs[TT];
    const int b = blockIdx.y;
    const int tid = threadIdx.x;
    const int total = block_scan_1024(dur, b, s_cs);
    if (blockIdx.x == 0 && tid == 0) out_total[b] = (float)total;

    const int f = blockIdx.x * 1024 + tid;
    uint16_t t = 0xFFFFu;
    if (f < total) {
        int lo = 0, hi = TT;
        while (lo < hi) {
            int mid = (lo + hi) >> 1;
            if (s_cs[mid] <= f) lo = mid + 1; else hi = mid;
        }
        t = (uint16_t)min(lo, TT - 1);
    }
    tok[b * MAXMEL + f] = t;
}

// 512 threads = 16 frames x 32 lanes; 3 float4 ld then 3 nt float4 st per thread
// (loads issued back-to-back before stores for explicit VMEM ILP).
__global__ __launch_bounds__(512) void lr_expand_tok16(const float* __restrict__ x,
                                                       const uint16_t* __restrict__ tok,
                                                       float* __restrict__ out) {
    const int b = blockIdx.y;
    const int frame = blockIdx.x * 16 + (threadIdx.x >> 5);
    const int lane = threadIdx.x & 31;
    const uint32_t t = tok[b * MAXMEL + frame];
    f4* outp = (f4*)(out + ((size_t)b * MAXMEL + frame) * CC);
    if (t != 0xFFFFu) {
        const f4* src = (const f4*)(x + ((size_t)b * TT + t) * CC);
        f4 v0 = src[lane];
        f4 v1 = src[lane + 32];
        f4 v2 = src[lane + 64];
        __builtin_nontemporal_store(v0, &outp[lane]);
        __builtin_nontemporal_store(v1, &outp[lane + 32]);
        __builtin_nontemporal_store(v2, &outp[lane + 64]);
    } else {
        const f4 z = {0.f, 0.f, 0.f, 0.f};
        __builtin_nontemporal_store(z, &outp[lane]);
        __builtin_nontemporal_store(z, &outp[lane + 32]);
        __builtin_nontemporal_store(z, &outp[lane + 64]);
    }
}

// ---------- Path B: cs only (128 KB ws, proven safe) + staged LDS search ----------

__global__ __launch_bounds__(1024) void lr_scan_cs(const int* __restrict__ dur,
                                                   int* __restrict__ cs,
                                                   float* __restrict__ out_total) {
    __shared__ int s_cs[TT];
    const int b = blockIdx.x;
    const int tid = threadIdx.x;
    const int total = block_scan_1024(dur, b, s_cs);
    cs[b * TT + tid] = s_cs[tid];
    if (tid == 0) out_total[b] = (float)total;
}

// 1024 threads = 64 frames x 16 lanes; 6 float4 per lane; cs staged once/block.
__global__ __launch_bounds__(1024) void lr_expand_search(const float* __restrict__ x,
                                                         const int* __restrict__ cs,
                                                         float* __restrict__ out) {
    __shared__ int s_cs[TT];
    const int b = blockIdx.y;
    const int tid = threadIdx.x;
    s_cs[tid] = cs[b * TT + tid];
    __syncthreads();
    const int total = s_cs[TT - 1];
    const int frame = blockIdx.x * 64 + (tid >> 4);
    const int lane = tid & 15;
    f4* outp = (f4*)(out + ((size_t)b * MAXMEL + frame) * CC);
    if (frame < total) {
        int lo = 0, hi = TT;
        while (lo < hi) {
            int mid = (lo + hi) >> 1;
            if (s_cs[mid] <= frame) lo = mid + 1; else hi = mid;
        }
        const int t = min(lo, TT - 1);
        const f4* src = (const f4*)(x + ((size_t)b * TT + t) * CC);
        #pragma unroll
        for (int k = 0; k < 6; ++k) outp[lane + k * 16] = src[lane + k * 16];
    } else {
        const f4 z = {0.f, 0.f, 0.f, 0.f};
        #pragma unroll
        for (int k = 0; k < 6; ++k) outp[lane + k * 16] = z;
    }
}

extern "C" void kernel_launch(void* const* d_in, const int* in_sizes, int n_in,
                              void* d_out, int out_size, void* d_ws, size_t ws_size,
                              hipStream_t stream) {
    const float* x = (const float*)d_in[0];
    const int* dur = (const int*)d_in[1];  // reference int64 -> int32 on device per harness
    float* out = (float*)d_out;
    float* out_total = out + (size_t)BB * MAXMEL * CC;  // 32 floats at the tail

    if (ws_size >= (size_t)BB * MAXMEL * sizeof(uint16_t)) {
        uint16_t* tok = (uint16_t*)d_ws;  // 256 KB
        lr_scan_tok16<<<dim3(4, BB), 1024, 0, stream>>>(dur, tok, out_total);
        lr_expand_tok16<<<dim3(MAXMEL / 16, BB), 512, 0, stream>>>(x, tok, out);
    } else {
        int* cs = (int*)d_ws;  // 128 KB
        lr_scan_cs<<<BB, 1024, 0, stream>>>(dur, cs, out_total);
        lr_expand_search<<<dim3(MAXMEL / 64, BB), 1024, 0, stream>>>(x, cs, out);
    }
}